// Round 14
// baseline (633.167 us; speedup 1.0000x reference)
//
#include <hip/hip_runtime.h>
#include <stdint.h>

typedef unsigned short u16;
typedef unsigned int u32;
typedef __bf16 bf16x8 __attribute__((ext_vector_type(8)));
typedef float f32x4 __attribute__((ext_vector_type(4)));
typedef _Float16 h2 __attribute__((ext_vector_type(2)));

#define N_NODES 65536
#define N_EDGES 131072
#define N_GRAPHS 2048

static __device__ __forceinline__ float bf2f(u16 u) {
  union { u32 u; float f; } v; v.u = ((u32)u) << 16; return v.f;
}
static __device__ __forceinline__ u16 f2bf(float f) {
  union { float f; u32 u; } v; v.f = f;
  u32 r = v.u + 0x7fffu + ((v.u >> 16) & 1u);
  return (u16)(r >> 16);
}
static __device__ __forceinline__ void gl16(const void* g, void* l) {
  __builtin_amdgcn_global_load_lds(
      (__attribute__((address_space(1))) void*)(g),
      (__attribute__((address_space(3))) void*)(l), 16, 0, 0);
}
static __device__ __forceinline__ h2 b2h2(u32 u) {
  union { u32 u; h2 h; } v; v.u = u; return v.h;
}
static __device__ __forceinline__ u32 pk2h(float a, float b) {
  union { _Float16 h[2]; u32 u; } v;
  v.h[0] = (_Float16)a; v.h[1] = (_Float16)b; return v.u;
}
#if __has_builtin(__builtin_amdgcn_fdot2)
#define FDOT2(a, b, c) __builtin_amdgcn_fdot2((a), (b), (c), false)
#else
#define FDOT2(a, b, c) \
  ((c) + (float)(a)[0] * (float)(b)[0] + (float)(a)[1] * (float)(b)[1])
#endif

// ---------------------------------------------------------------------------
// Heavy GEMM, BK=128, A-stage-only: 128x128 tile, 4 waves.
// A staged via gl16 into 32KB LDS with XOR-slot swizzle (slot^(row&15));
// B (weights, L2-resident, shared across same-bn blocks) read DIRECT from
// global per fragment -- identical bits to the former swizzled-LDS path
// (LDS slot s held col-slot s^row; reading slot (kk*4+lg)^lr at row lr gave
// col-slot kk*4+lg).  LDS 64->32KB + 8 fewer gl16/tile -> 4 blocks/CU.
// One barrier-pair + drain per 128 K.  XCD swizzle (T1).  K%128==0.
// ---------------------------------------------------------------------------
template <int EPI>
__global__ __launch_bounds__(256) void gemm_bt128(
    const u16* __restrict__ A, const u16* __restrict__ W,
    const float* __restrict__ bias, const float* __restrict__ scale,
    const float* __restrict__ shift, u16* __restrict__ Cp,
    int K, int ldc) {
  __shared__ u16 As[128 * 128];
  const u32 gx = gridDim.x;
  const u32 nwg = gx * gridDim.y;
  u32 lid = blockIdx.y * gx + blockIdx.x;
  if ((nwg & 7u) == 0u) {
    const u32 cpx = nwg >> 3;
    lid = (lid & 7u) * cpx + (lid >> 3);
  }
  const int bm = (int)(lid / gx) * 128;
  const int bn = (int)(lid % gx) * 128;
  const int tid = threadIdx.x;
  const int lane = tid & 63;
  const int wid = tid >> 6;
  const int wr = wid >> 1, wc = wid & 1;
  const int lg = lane >> 4, lr = lane & 15;

  f32x4 acc[4][4];
#pragma unroll
  for (int i = 0; i < 4; ++i)
#pragma unroll
    for (int j = 0; j < 4; ++j) acc[i][j] = (f32x4){0.f, 0.f, 0.f, 0.f};

  const int srow16 = tid >> 4;
  const int gslot = ((tid & 15) ^ srow16) * 8;
  const u16* Ag[8];
#pragma unroll
  for (int p = 0; p < 8; ++p)
    Ag[p] = A + (size_t)(bm + p * 16 + srow16) * K + gslot;
  u16* dA = &As[tid * 8];

  const u16* Wr[4];
#pragma unroll
  for (int j = 0; j < 4; ++j)
    Wr[j] = W + (size_t)(bn + wc * 64 + j * 16 + lr) * K;

  for (int k0 = 0; k0 < K; k0 += 128) {
#pragma unroll
    for (int p = 0; p < 8; ++p) gl16(Ag[p] + k0, dA + p * 2048);
    __syncthreads();  // drains vmcnt per compiler semantics
#pragma unroll
    for (int kk = 0; kk < 4; ++kk) {
      const int slot = ((kk * 4 + lg) ^ lr) * 8;
      const int gcol8 = k0 + (kk * 4 + lg) * 8;
      bf16x8 af[4], bfv[4];
#pragma unroll
      for (int i = 0; i < 4; ++i)
        af[i] = *(const bf16x8*)&As[(wr * 64 + i * 16 + lr) * 128 + slot];
#pragma unroll
      for (int j = 0; j < 4; ++j)
        bfv[j] = *(const bf16x8*)&Wr[j][gcol8];
#pragma unroll
      for (int i = 0; i < 4; ++i)
#pragma unroll
        for (int j = 0; j < 4; ++j)
          acc[i][j] = __builtin_amdgcn_mfma_f32_16x16x32_bf16(
              af[i], bfv[j], acc[i][j], 0, 0, 0);
    }
    __syncthreads();
  }

#pragma unroll
  for (int i = 0; i < 4; ++i) {
#pragma unroll
    for (int j = 0; j < 4; ++j) {
#pragma unroll
      for (int r = 0; r < 4; ++r) {
        const int grow = bm + wr * 64 + i * 16 + lg * 4 + r;
        const int gcol = bn + wc * 64 + j * 16 + lr;
        float v = acc[i][j][r] + bias[gcol];
        v = fmaxf(v, 0.f);
        if (EPI == 1) v = v * scale[gcol] + shift[gcol];
        Cp[(size_t)grow * ldc + gcol] = f2bf(v);
      }
    }
  }
}

// ---------------------------------------------------------------------------
// BK=32 GEMM (K=96 layer-1 GEMM1): round-4 proven version.
// ---------------------------------------------------------------------------
template <int EPI>
__global__ __launch_bounds__(256) void gemm_bt(
    const u16* __restrict__ A, const u16* __restrict__ W,
    const float* __restrict__ bias, const float* __restrict__ scale,
    const float* __restrict__ shift, u16* __restrict__ Cp,
    int K, int ldc, int coff) {
  __shared__ u16 As[128 * 32];
  __shared__ u16 Bs[128 * 32];
  const u32 gx = gridDim.x;
  const u32 nwg = gx * gridDim.y;
  u32 lid = blockIdx.y * gx + blockIdx.x;
  if ((nwg & 7u) == 0u) {
    const u32 cpx = nwg >> 3;
    lid = (lid & 7u) * cpx + (lid >> 3);
  }
  const int bm = (int)(lid / gx) * 128;
  const int bn = (int)(lid % gx) * 128;
  const int tid = threadIdx.x;
  const int lane = tid & 63;
  const int wid = tid >> 6;
  const int wr = wid >> 1, wc = wid & 1;
  const int lg = lane >> 4, lr = lane & 15;

  f32x4 acc[4][4];
#pragma unroll
  for (int i = 0; i < 4; ++i)
#pragma unroll
    for (int j = 0; j < 4; ++j) acc[i][j] = (f32x4){0.f, 0.f, 0.f, 0.f};

  const int srow = tid >> 2;
  const int c8 = (tid & 3) * 8;
  const u16* Ag0 = A + (size_t)(bm + srow) * K + c8;
  const u16* Ag1 = A + (size_t)(bm + 64 + srow) * K + c8;
  const u16* Wg0 = W + (size_t)(bn + srow) * K + c8;
  const u16* Wg1 = W + (size_t)(bn + 64 + srow) * K + c8;
  u16* lA0 = &As[tid * 8];
  u16* lA1 = &As[2048 + tid * 8];
  u16* lB0 = &Bs[tid * 8];
  u16* lB1 = &Bs[2048 + tid * 8];

  for (int k0 = 0; k0 < K; k0 += 32) {
    gl16(Ag0 + k0, lA0);
    gl16(Ag1 + k0, lA1);
    gl16(Wg0 + k0, lB0);
    gl16(Wg1 + k0, lB1);
    __syncthreads();
    bf16x8 af[4], bfv[4];
#pragma unroll
    for (int i = 0; i < 4; ++i)
      af[i] = *(const bf16x8*)&As[(wr * 64 + i * 16 + lr) * 32 + lg * 8];
#pragma unroll
    for (int j = 0; j < 4; ++j)
      bfv[j] = *(const bf16x8*)&Bs[(wc * 64 + j * 16 + lr) * 32 + lg * 8];
#pragma unroll
    for (int i = 0; i < 4; ++i)
#pragma unroll
      for (int j = 0; j < 4; ++j)
        acc[i][j] = __builtin_amdgcn_mfma_f32_16x16x32_bf16(af[i], bfv[j],
                                                            acc[i][j], 0, 0, 0);
    __syncthreads();
  }

#pragma unroll
  for (int i = 0; i < 4; ++i) {
#pragma unroll
    for (int j = 0; j < 4; ++j) {
#pragma unroll
      for (int r = 0; r < 4; ++r) {
        const int grow = bm + wr * 64 + i * 16 + lg * 4 + r;
        const int gcol = bn + wc * 64 + j * 16 + lr;
        float v = acc[i][j][r] + bias[gcol];
        v = fmaxf(v, 0.f);
        if (EPI == 1) v = v * scale[gcol] + shift[gcol];
        Cp[(size_t)grow * ldc + coff + gcol] = f2bf(v);
      }
    }
  }
}

// ---------------------------------------------------------------------------
// Fused head (proven R13): 16 graph rows per block, intermediates in LDS
// fragment-major; swapped-operand mfma(b,a) epilogue mapping.
// ---------------------------------------------------------------------------
static __device__ __forceinline__ void head_stage2(
    const u16* Sa, u16* So, int kofs, const u16* __restrict__ W, int ldw,
    const float* __restrict__ bias, int KT, int w, int l, int lr, int lg) {
  f32x4 acc[2];
  acc[0] = (f32x4){0.f, 0.f, 0.f, 0.f};
  acc[1] = (f32x4){0.f, 0.f, 0.f, 0.f};
  for (int t = 0; t < KT; ++t) {
    bf16x8 a = *(const bf16x8*)&Sa[t * 512 + l * 8];
#pragma unroll
    for (int j = 0; j < 2; ++j) {
      bf16x8 b = *(const bf16x8*)&W[(size_t)(w * 32 + j * 16 + lr) * ldw +
                                    t * 32 + lg * 8];
      acc[j] = __builtin_amdgcn_mfma_f32_16x16x32_bf16(b, a, acc[j], 0, 0, 0);
    }
  }
#pragma unroll
  for (int j = 0; j < 2; ++j) {
    const int c0 = w * 32 + j * 16 + lg * 4;
    const float4 bs = *(const float4*)&bias[c0];
    const float v0 = fmaxf(acc[j][0] + bs.x, 0.f);
    const float v1 = fmaxf(acc[j][1] + bs.y, 0.f);
    const float v2 = fmaxf(acc[j][2] + bs.z, 0.f);
    const float v3 = fmaxf(acc[j][3] + bs.w, 0.f);
    uint2 r;
    r.x = (u32)f2bf(v0) | ((u32)f2bf(v1) << 16);
    r.y = (u32)f2bf(v2) | ((u32)f2bf(v3) << 16);
    const int k0 = kofs + c0;
    *(uint2*)&So[(k0 >> 5) * 512 + ((k0 & 31) >> 3) * 128 + lr * 8 + (k0 & 7)] = r;
  }
}

static __device__ __forceinline__ void head_stage1(
    const u16* Sa, u16* So, int kofs, const u16* __restrict__ W, int ldw,
    const float* __restrict__ bias, int KT, int w, int l, int lr, int lg) {
  f32x4 acc = (f32x4){0.f, 0.f, 0.f, 0.f};
  for (int t = 0; t < KT; ++t) {
    bf16x8 a = *(const bf16x8*)&Sa[t * 512 + l * 8];
    bf16x8 b = *(const bf16x8*)&W[(size_t)(w * 16 + lr) * ldw + t * 32 + lg * 8];
    acc = __builtin_amdgcn_mfma_f32_16x16x32_bf16(b, a, acc, 0, 0, 0);
  }
  const int c0 = w * 16 + lg * 4;
  const float4 bs = *(const float4*)&bias[c0];
  const float v0 = fmaxf(acc[0] + bs.x, 0.f);
  const float v1 = fmaxf(acc[1] + bs.y, 0.f);
  const float v2 = fmaxf(acc[2] + bs.z, 0.f);
  const float v3 = fmaxf(acc[3] + bs.w, 0.f);
  uint2 r;
  r.x = (u32)f2bf(v0) | ((u32)f2bf(v1) << 16);
  r.y = (u32)f2bf(v2) | ((u32)f2bf(v3) << 16);
  const int k0 = kofs + c0;
  *(uint2*)&So[(k0 >> 5) * 512 + ((k0 & 31) >> 3) * 128 + lr * 8 + (k0 & 7)] = r;
}

__global__ __launch_bounds__(512) void head_fused(
    const u16* __restrict__ gbuf, const u16* __restrict__ fingb,
    const u16* __restrict__ wfcg, const float* __restrict__ fcg_b,
    const u16* __restrict__ wfp1, const float* __restrict__ fp1_b,
    const u16* __restrict__ wfp2, const float* __restrict__ fp2_b,
    const u16* __restrict__ wfb1, const float* __restrict__ fb1_b,
    const u16* __restrict__ wfb2, const float* __restrict__ fb2_b,
    const u16* __restrict__ wfb3, const float* __restrict__ fb3_b,
    const float* __restrict__ fb4_w, const float* __restrict__ fb4_b,
    float* __restrict__ out) {
  __shared__ u16 S[26624];
  const int g0 = blockIdx.x * 16;
  const int tid = threadIdx.x;
  const int w = tid >> 6, l = tid & 63;
  const int lr = l & 15, lg = l >> 4;

  for (int v = tid; v < 1024; v += 512) {
    const int r = v >> 6, c0 = (v & 63) * 8;
    uint4 d = *(const uint4*)&gbuf[(size_t)(g0 + r) * 512 + c0];
    *(uint4*)&S[(c0 >> 5) * 512 + ((c0 & 31) >> 3) * 128 + r * 8] = d;
  }
  __syncthreads();
  head_stage2(&S[0], &S[8192], 0, wfcg, 512, fcg_b, 16, w, l, lr, lg);
  {
    f32x4 acc = (f32x4){0.f, 0.f, 0.f, 0.f};
    for (int t = 0; t < 47; ++t) {
      bf16x8 a = *(const bf16x8*)&fingb[(size_t)(g0 + lr) * 1504 + t * 32 + lg * 8];
      bf16x8 b = *(const bf16x8*)&wfp1[(size_t)(w * 16 + lr) * 1504 + t * 32 + lg * 8];
      acc = __builtin_amdgcn_mfma_f32_16x16x32_bf16(b, a, acc, 0, 0, 0);
    }
    const int c0 = w * 16 + lg * 4;
    const float4 bs = *(const float4*)&fp1_b[c0];
    const float v0 = fmaxf(acc[0] + bs.x, 0.f);
    const float v1 = fmaxf(acc[1] + bs.y, 0.f);
    const float v2 = fmaxf(acc[2] + bs.z, 0.f);
    const float v3 = fmaxf(acc[3] + bs.w, 0.f);
    uint2 r;
    r.x = (u32)f2bf(v0) | ((u32)f2bf(v1) << 16);
    r.y = (u32)f2bf(v2) | ((u32)f2bf(v3) << 16);
    *(uint2*)&S[16384 + (c0 >> 5) * 512 + ((c0 & 31) >> 3) * 128 + lr * 8 +
                (c0 & 7)] = r;
  }
  __syncthreads();
  head_stage2(&S[16384], &S[8192], 256, wfp2, 128, fp2_b, 4, w, l, lr, lg);
  __syncthreads();
  head_stage2(&S[8192], &S[18432], 0, wfb1, 512, fb1_b, 16, w, l, lr, lg);
  __syncthreads();
  head_stage1(&S[18432], &S[22528], 0, wfb2, 256, fb2_b, 8, w, l, lr, lg);
  __syncthreads();
  if (w < 4) {
    f32x4 acc = (f32x4){0.f, 0.f, 0.f, 0.f};
    for (int t = 0; t < 4; ++t) {
      bf16x8 a = *(const bf16x8*)&S[22528 + t * 512 + l * 8];
      bf16x8 b = *(const bf16x8*)&wfb3[(size_t)(w * 16 + lr) * 128 + t * 32 + lg * 8];
      acc = __builtin_amdgcn_mfma_f32_16x16x32_bf16(b, a, acc, 0, 0, 0);
    }
    const int c0 = w * 16 + lg * 4;
    float* H3 = (float*)&S[24576];
#pragma unroll
    for (int r = 0; r < 4; ++r)
      H3[lr * 64 + c0 + r] = fmaxf(acc[r] + fb3_b[c0 + r], 0.f);
  }
  __syncthreads();
  if (tid < 32) {
    const int r = tid >> 1, o = tid & 1;
    const float* H3 = (const float*)&S[24576];
    float s = fb4_b[o];
#pragma unroll 8
    for (int k = 0; k < 64; ++k) s += H3[r * 64 + k] * fb4_w[o * 64 + k];
    out[(size_t)(g0 + r) * 2 + o] = 1.f / (1.f + expf(-s));
  }
}

// ---------------------------------------------------------------------------
// CSR build (edge list is static): deg histogram -> exclusive scan -> scatter.
// ---------------------------------------------------------------------------
__global__ void hist_deg(const int* __restrict__ dst, int* __restrict__ deg) {
  int e = blockIdx.x * blockDim.x + threadIdx.x;
  if (e < N_EDGES) atomicAdd(&deg[dst[e]], 1);
}

__global__ __launch_bounds__(1024) void scan_rowptr(const int* __restrict__ deg,
                                                    int* __restrict__ rowptr) {
  __shared__ int lds[1024];
  const int t = threadIdx.x;
  const int base = t * 64;
  int s = 0;
  for (int i = 0; i < 64; ++i) s += deg[base + i];
  lds[t] = s;
  __syncthreads();
  for (int ofs = 1; ofs < 1024; ofs <<= 1) {
    int v = (t >= ofs) ? lds[t - ofs] : 0;
    __syncthreads();
    lds[t] += v;
    __syncthreads();
  }
  int run = (t == 0) ? 0 : lds[t - 1];
  for (int i = 0; i < 64; ++i) {
    rowptr[base + i] = run;
    run += deg[base + i];
  }
  if (t == 1023) rowptr[65536] = run;
}

// consumes deg (countdown to zero); slot order within a node is arbitrary
__global__ void scatter_csr(const int* __restrict__ dst,
                            const int* __restrict__ rowptr,
                            int* __restrict__ deg, int* __restrict__ csr) {
  int e = blockIdx.x * blockDim.x + threadIdx.x;
  if (e >= N_EDGES) return;
  int d = dst[e];
  int pos = atomicSub(&deg[d], 1) - 1;
  csr[rowptr[d] + pos] = e;
}

// CSR-ordered edge data: src_s[i] = esrc[csr[i]]; ea16[i] = f16x2-packed ea row.
__global__ void prep_edges(const int* __restrict__ csr,
                           const int* __restrict__ esrc,
                           const float* __restrict__ ea,
                           int* __restrict__ src_s, u32* __restrict__ ea16) {
  int i = blockIdx.x * blockDim.x + threadIdx.x;
  if (i >= N_EDGES) return;
  const int eid = csr[i];
  src_s[i] = esrc[eid];
  const float* er = ea + (size_t)eid * 10;
  u32* o = ea16 + (size_t)i * 5;
  o[0] = pk2h(er[0], er[1]);
  o[1] = pk2h(er[2], er[3]);
  o[2] = pk2h(er[4], er[5]);
  o[3] = pk2h(er[6], er[7]);
  o[4] = pk2h(er[8], er[9]);
}

// Edge-lin weights -> packed f16 pairs, layers 1 (78 rows), 2 and 3 (512 each).
__global__ void ew_h16(const float* __restrict__ ew1, const float* __restrict__ ew2,
                       const float* __restrict__ ew3, u32* __restrict__ o1,
                       u32* __restrict__ o2, u32* __restrict__ o3) {
  int i = blockIdx.x * blockDim.x + threadIdx.x;  // 0..1101
  const float* src;
  u32* dst;
  if (i < 512) { src = ew2 + (size_t)i * 10; dst = o2 + i * 5; }
  else if (i < 1024) { src = ew3 + (size_t)(i - 512) * 10; dst = o3 + (i - 512) * 5; }
  else if (i < 1102) { src = ew1 + (size_t)(i - 1024) * 10; dst = o1 + (i - 1024) * 5; }
  else return;
#pragma unroll
  for (int k = 0; k < 5; ++k) dst[k] = pk2h(src[2 * k], src[2 * k + 1]);
}

// ---------------------------------------------------------------------------
// Node-centric fused aggregation, f16-dot2 variant (proven R11).
// ---------------------------------------------------------------------------
__global__ __launch_bounds__(128) void gather512d(
    const int* __restrict__ rowptr, const int* __restrict__ src_s,
    const u32* __restrict__ ea16, const u32* __restrict__ ew16,
    const float* __restrict__ eb, const u16* __restrict__ H,
    u16* __restrict__ T) {
  const int t = threadIdx.x;
  const int c4 = t * 4;
  h2 w[4][5];
#pragma unroll
  for (int j = 0; j < 4; ++j)
#pragma unroll
    for (int k = 0; k < 5; ++k) w[j][k] = b2h2(ew16[(c4 + j) * 5 + k]);
  float eb4[4];
#pragma unroll
  for (int j = 0; j < 4; ++j) eb4[j] = eb[c4 + j];

  const int dend = blockIdx.x * 8 + 8;
  for (int d = blockIdx.x * 8; d < dend; ++d) {
    uint2 hv = *(const uint2*)&H[(size_t)d * 512 + c4];
    float a0 = bf2f((u16)(hv.x & 0xffffu)), a1 = bf2f((u16)(hv.x >> 16));
    float a2 = bf2f((u16)(hv.y & 0xffffu)), a3 = bf2f((u16)(hv.y >> 16));
    const int i1 = rowptr[d + 1];
#pragma unroll 2
    for (int i = rowptr[d]; i < i1; ++i) {
      const int s = src_s[i];
      const u32* ep = ea16 + (size_t)i * 5;
      const h2 e0 = b2h2(ep[0]), e1 = b2h2(ep[1]), e2 = b2h2(ep[2]),
               e3 = b2h2(ep[3]), e4 = b2h2(ep[4]);
      uint2 hs = *(const uint2*)&H[(size_t)s * 512 + c4];
      float h0 = bf2f((u16)(hs.x & 0xffffu)), h1 = bf2f((u16)(hs.x >> 16));
      float h2v = bf2f((u16)(hs.y & 0xffffu)), h3 = bf2f((u16)(hs.y >> 16));
      float l0 = eb4[0], l1 = eb4[1], l2 = eb4[2], l3 = eb4[3];
      l0 = FDOT2(e0, w[0][0], l0); l0 = FDOT2(e1, w[0][1], l0);
      l0 = FDOT2(e2, w[0][2], l0); l0 = FDOT2(e3, w[0][3], l0);
      l0 = FDOT2(e4, w[0][4], l0);
      l1 = FDOT2(e0, w[1][0], l1); l1 = FDOT2(e1, w[1][1], l1);
      l1 = FDOT2(e2, w[1][2], l1); l1 = FDOT2(e3, w[1][3], l1);
      l1 = FDOT2(e4, w[1][4], l1);
      l2 = FDOT2(e0, w[2][0], l2); l2 = FDOT2(e1, w[2][1], l2);
      l2 = FDOT2(e2, w[2][2], l2); l2 = FDOT2(e3, w[2][3], l2);
      l2 = FDOT2(e4, w[2][4], l2);
      l3 = FDOT2(e0, w[3][0], l3); l3 = FDOT2(e1, w[3][1], l3);
      l3 = FDOT2(e2, w[3][2], l3); l3 = FDOT2(e3, w[3][3], l3);
      l3 = FDOT2(e4, w[3][4], l3);
      a0 += fmaxf(h0 + l0, 0.f);
      a1 += fmaxf(h1 + l1, 0.f);
      a2 += fmaxf(h2v + l2, 0.f);
      a3 += fmaxf(h3 + l3, 0.f);
    }
    uint2 r;
    r.x = (u32)f2bf(a0) | ((u32)f2bf(a1) << 16);
    r.y = (u32)f2bf(a2) | ((u32)f2bf(a3) << 16);
    *(uint2*)&T[(size_t)d * 512 + c4] = r;
  }
}

// Layer-1 variant, f16-dot2 (proven R12).
__global__ __launch_bounds__(128) void gather78d(
    const int* __restrict__ rowptr, const int* __restrict__ src_s,
    const u32* __restrict__ ea16, const u32* __restrict__ ew16,
    const float* __restrict__ eb, const float* __restrict__ X,
    u16* __restrict__ T) {
  const int t = threadIdx.x;
  const bool act = t < 78;
  h2 w[5];
  float ebv = 0.f;
  if (act) {
#pragma unroll
    for (int k = 0; k < 5; ++k) w[k] = b2h2(ew16[t * 5 + k]);
    ebv = eb[t];
  }
  const int dend = blockIdx.x * 8 + 8;
  for (int d = blockIdx.x * 8; d < dend; ++d) {
    float acc = act ? X[(size_t)d * 78 + t] : 0.f;
    const int i1 = rowptr[d + 1];
    for (int i = rowptr[d]; i < i1; ++i) {
      const int s = src_s[i];
      const u32* ep = ea16 + (size_t)i * 5;
      const h2 e0 = b2h2(ep[0]), e1 = b2h2(ep[1]), e2 = b2h2(ep[2]),
               e3 = b2h2(ep[3]), e4 = b2h2(ep[4]);
      if (act) {
        float el = ebv;
        el = FDOT2(e0, w[0], el); el = FDOT2(e1, w[1], el);
        el = FDOT2(e2, w[2], el); el = FDOT2(e3, w[3], el);
        el = FDOT2(e4, w[4], el);
        acc += fmaxf(X[(size_t)s * 78 + t] + el, 0.f);
      }
    }
    if (t < 96) T[(size_t)d * 96 + t] = act ? f2bf(acc) : (u16)0;
  }
}

// ---------------------------------------------------------------------------
// Consolidated prep: 12 f32->bf16 (pad) conversions in one launch.
// ---------------------------------------------------------------------------
struct CvtJob { const float* in; u16* out; int cin; int cout; };
struct CvtJobs { CvtJob j[12]; int blk_ofs[13]; };

__global__ __launch_bounds__(256) void cvt_multi(CvtJobs jb, int njobs) {
  int b = blockIdx.x;
  int ji = 0;
  while (ji + 1 < njobs && b >= jb.blk_ofs[ji + 1]) ++ji;
  const CvtJob J = jb.j[ji];
  int idx = (b - jb.blk_ofs[ji]) * 256 + threadIdx.x;
  int r = idx / J.cout, c = idx - r * J.cout;
  int tot_blocks = jb.blk_ofs[ji + 1] - jb.blk_ofs[ji];
  if (idx >= tot_blocks * 256) return;
  if (idx >= ((tot_blocks * 256) / J.cout) * J.cout && c >= J.cout) return;
  J.out[idx] = (c < J.cin) ? f2bf(J.in[(size_t)r * J.cin + c]) : (u16)0;
}

// BN folded to per-channel affine, all 3 layers in one launch
struct BnJobs { const float* g[3]; const float* b[3]; const float* m[3];
                const float* v[3]; };
__global__ void bn_affine3(BnJobs p, float* __restrict__ bnS) {
  int i = blockIdx.x * blockDim.x + threadIdx.x;  // 0..1535
  int l = i >> 9, c = i & 511;
  float s = p.g[l][c] * rsqrtf(p.v[l][c] + 1e-5f);
  bnS[l * 1024 + c] = s;
  bnS[l * 1024 + 512 + c] = p.b[l][c] - p.m[l][c] * s;
}

// segment starts from sorted batch: start[g] = first node with batch >= g
__global__ void seg_starts(const int* __restrict__ batch, int* __restrict__ start,
                           int n, int ngraphs) {
  int i = blockIdx.x * blockDim.x + threadIdx.x;
  if (i >= n) return;
  int b = batch[i];
  int prev = (i == 0) ? -1 : batch[i - 1];
  for (int g = prev + 1; g <= b; ++g) start[g] = i;
  if (i == n - 1)
    for (int g = b + 1; g <= ngraphs; ++g) start[g] = n;
}

// plain f32 -> bf16 with column padding (finger, runs after GNN layers)
__global__ void cvt_pad(const float* __restrict__ in, u16* __restrict__ out,
                        int rows, int cin, int cout) {
  int idx = blockIdx.x * blockDim.x + threadIdx.x;
  if (idx >= rows * cout) return;
  int rrow = idx / cout, j = idx - rrow * cout;
  out[idx] = (j < cin) ? f2bf(in[(size_t)rrow * cin + j]) : (u16)0;
}

// global_add_pool (block per graph, thread per channel), bf16 in/out
__global__ void pool_sum(const u16* __restrict__ H, const int* __restrict__ start,
                         u16* __restrict__ g) {
  int gi = blockIdx.x, c = threadIdx.x;
  int s = start[gi], e = start[gi + 1];
  float acc = 0.f;
  for (int i = s; i < e; ++i) acc += bf2f(H[(size_t)i * 512 + c]);
  g[gi * 512 + c] = f2bf(acc);
}

// ---------------------------------------------------------------------------
#define CDIV(a, b) (((a) + (b)-1) / (b))

extern "C" void kernel_launch(void* const* d_in, const int* in_sizes, int n_in,
                              void* d_out, int out_size, void* d_ws, size_t ws_size,
                              hipStream_t stream) {
  const float* x = (const float*)d_in[0];
  const float* finger = (const float*)d_in[1];
  const float* ea = (const float*)d_in[2];
  const int* eidx = (const int*)d_in[3];
  const int* batch = (const int*)d_in[4];
  const int* esrc = eidx;
  const int* edst = eidx + N_EDGES;

  const float* P[49];
  for (int i = 5; i < 49; ++i) P[i] = (const float*)d_in[i];
  const float* fcg_w = P[35]; const float* fcg_b = P[36];
  const float* fp1_w = P[37]; const float* fp1_b = P[38];
  const float* fp2_w = P[39]; const float* fp2_b = P[40];
  const float* fb1_w = P[41]; const float* fb1_b = P[42];
  const float* fb2_w = P[43]; const float* fb2_b = P[44];
  const float* fb3_w = P[45]; const float* fb3_b = P[46];
  const float* fb4_w = P[47]; const float* fb4_b = P[48];

  // ---- workspace layout (~142 MB total) ----
  size_t off = 0;
  char* base = (char*)d_ws;
  auto alloc = [&](size_t bytes) -> void* {
    void* p = base + off;
    off = (off + bytes + 255) & ~(size_t)255;
    return p;
  };
  char* BA = (char*)alloc((size_t)N_NODES * 512 * 2);  // ping buffer (67 MB)
  char* BB = (char*)alloc((size_t)N_NODES * 512 * 2);  // pong buffer (67 MB)
  u16* w11 = (u16*)alloc(256 * 96 * 2);
  u16* w12 = (u16*)alloc(512 * 256 * 2);
  u16* w21 = (u16*)alloc(512 * 512 * 2);
  u16* w22 = (u16*)alloc(512 * 512 * 2);
  u16* w31 = (u16*)alloc(512 * 512 * 2);
  u16* w32 = (u16*)alloc(512 * 512 * 2);
  u16* wfcg = (u16*)alloc(256 * 512 * 2);
  u16* wfp1 = (u16*)alloc(128 * 1504 * 2);
  u16* wfp2 = (u16*)alloc(256 * 128 * 2);
  u16* wfb1 = (u16*)alloc(256 * 512 * 2);
  u16* wfb2 = (u16*)alloc(128 * 256 * 2);
  u16* wfb3 = (u16*)alloc(64 * 128 * 2);
  float* bnS = (float*)alloc(6 * 512 * 4);
  int* start = (int*)alloc(2049 * 4);
  int* deg = (int*)alloc(65536 * 4);
  int* rowptr = (int*)alloc(65537 * 4);
  int* csr = (int*)alloc(131072 * 4);
  int* src_s = (int*)alloc(131072 * 4);
  u32* ea16 = (u32*)alloc((size_t)131072 * 5 * 4);
  u32* ew16a = (u32*)alloc(512 * 5 * 4);
  u32* ew16b = (u32*)alloc(512 * 5 * 4);
  u32* ew16c = (u32*)alloc(128 * 5 * 4);
  if (off > ws_size) return;  // workspace insufficient; bail

  // head buffers carved from BA (free after the GNN layers)
  u16* fingb = (u16*)BA;                  // 2048*1504*2 = 6,160,384 B
  u16* gbuf = (u16*)(BA + 6160384);       // 2048*512*2  = 2,097,152 B

  // ---- consolidated parameter prep (1 launch for 12 conversions) ----
  {
    CvtJobs jb;
    const float* ins[12] = {P[5 + 2], P[5 + 4], P[15 + 2], P[15 + 4], P[25 + 2],
                            P[25 + 4], fcg_w, fp1_w, fp2_w, fb1_w, fb2_w, fb3_w};
    u16* outs[12] = {w11, w12, w21, w22, w31, w32, wfcg, wfp1, wfp2, wfb1,
                     wfb2, wfb3};
    int rows[12] = {256, 512, 512, 512, 512, 512, 256, 128, 256, 256, 128, 64};
    int cins[12] = {78, 256, 512, 512, 512, 512, 512, 1489, 128, 512, 256, 128};
    int couts[12] = {96, 256, 512, 512, 512, 512, 512, 1504, 128, 512, 256, 128};
    int acc = 0;
    for (int i = 0; i < 12; ++i) {
      jb.j[i].in = ins[i]; jb.j[i].out = outs[i];
      jb.j[i].cin = cins[i]; jb.j[i].cout = couts[i];
      jb.blk_ofs[i] = acc;
      acc += CDIV(rows[i] * couts[i], 256);
    }
    jb.blk_ofs[12] = acc;
    cvt_multi<<<acc, 256, 0, stream>>>(jb, 12);
  }
  {
    BnJobs bj;
    for (int l = 0; l < 3; ++l) {
      int pb = 5 + 10 * l;
      bj.g[l] = P[pb + 6]; bj.b[l] = P[pb + 7];
      bj.m[l] = P[pb + 8]; bj.v[l] = P[pb + 9];
    }
    bn_affine3<<<6, 256, 0, stream>>>(bj, bnS);
  }
  seg_starts<<<CDIV(N_NODES, 256), 256, 0, stream>>>(batch, start, N_NODES, N_GRAPHS);
  ew_h16<<<5, 256, 0, stream>>>(P[5], P[15], P[25], ew16c, ew16a, ew16b);

  // ---- CSR build (once; edge list is static) ----
  hipMemsetAsync(deg, 0, 65536 * 4, stream);
  hist_deg<<<CDIV(N_EDGES, 256), 256, 0, stream>>>(edst, deg);
  scan_rowptr<<<1, 1024, 0, stream>>>(deg, rowptr);
  scatter_csr<<<CDIV(N_EDGES, 256), 256, 0, stream>>>(edst, rowptr, deg, csr);
  prep_edges<<<CDIV(N_EDGES, 256), 256, 0, stream>>>(csr, esrc, ea, src_s, ea16);

  // ---- layer 1 (Cin=78): T1->BB, U1->BA, H1->BB ----
  gather78d<<<N_NODES / 8, 128, 0, stream>>>(rowptr, src_s, ea16, ew16c, P[6], x,
                                             (u16*)BB);
  gemm_bt<0><<<dim3(2, 512), 256, 0, stream>>>((u16*)BB, w11, P[5 + 3], nullptr,
                                               nullptr, (u16*)BA, 96, 256, 0);
  gemm_bt128<1><<<dim3(4, 512), 256, 0, stream>>>((u16*)BA, w12, P[5 + 5], bnS,
                                                  bnS + 512, (u16*)BB, 256, 512);

  // ---- layer 2: H1 in BB -> T2 in BA -> U2 in BB -> H2 in BA ----
  gather512d<<<N_NODES / 8, 128, 0, stream>>>(rowptr, src_s, ea16, ew16a, P[16],
                                              (const u16*)BB, (u16*)BA);
  gemm_bt128<0><<<dim3(4, 512), 256, 0, stream>>>((u16*)BA, w21, P[15 + 3], nullptr,
                                                  nullptr, (u16*)BB, 512, 512);
  gemm_bt128<1><<<dim3(4, 512), 256, 0, stream>>>((u16*)BB, w22, P[15 + 5],
                                                  bnS + 1024, bnS + 1024 + 512,
                                                  (u16*)BA, 512, 512);

  // ---- layer 3: H2 in BA -> T3 in BB -> U3 in BA -> H3 in BB ----
  gather512d<<<N_NODES / 8, 128, 0, stream>>>(rowptr, src_s, ea16, ew16b, P[26],
                                              (const u16*)BA, (u16*)BB);
  gemm_bt128<0><<<dim3(4, 512), 256, 0, stream>>>((u16*)BB, w31, P[25 + 3], nullptr,
                                                  nullptr, (u16*)BA, 512, 512);
  gemm_bt128<1><<<dim3(4, 512), 256, 0, stream>>>((u16*)BA, w32, P[25 + 5],
                                                  bnS + 2048, bnS + 2048 + 512,
                                                  (u16*)BB, 512, 512);

  // ---- pool + fused head (H3 in BB; fingb/gbuf live in BA, now free) ----
  pool_sum<<<N_GRAPHS, 512, 0, stream>>>((const u16*)BB, start, gbuf);
  cvt_pad<<<CDIV(N_GRAPHS * 1504, 256), 256, 0, stream>>>(finger, fingb, N_GRAPHS,
                                                          1489, 1504);
  head_fused<<<N_GRAPHS / 16, 512, 0, stream>>>(
      gbuf, fingb, wfcg, fcg_b, wfp1, fp1_b, wfp2, fp2_b, wfb1, fb1_b, wfb2,
      fb2_b, wfb3, fb3_b, fb4_w, fb4_b, (float*)d_out);
}

// Round 15
// 481.957 us; speedup vs baseline: 1.3137x; 1.3137x over previous
//
#include <hip/hip_runtime.h>
#include <stdint.h>

typedef unsigned short u16;
typedef unsigned int u32;
typedef __bf16 bf16x8 __attribute__((ext_vector_type(8)));
typedef float f32x4 __attribute__((ext_vector_type(4)));
typedef _Float16 h2 __attribute__((ext_vector_type(2)));

#define N_NODES 65536
#define N_EDGES 131072
#define N_GRAPHS 2048

static __device__ __forceinline__ float bf2f(u16 u) {
  union { u32 u; float f; } v; v.u = ((u32)u) << 16; return v.f;
}
static __device__ __forceinline__ u16 f2bf(float f) {
  union { float f; u32 u; } v; v.f = f;
  u32 r = v.u + 0x7fffu + ((v.u >> 16) & 1u);
  return (u16)(r >> 16);
}
static __device__ __forceinline__ void gl16(const void* g, void* l) {
  __builtin_amdgcn_global_load_lds(
      (__attribute__((address_space(1))) void*)(g),
      (__attribute__((address_space(3))) void*)(l), 16, 0, 0);
}
static __device__ __forceinline__ h2 b2h2(u32 u) {
  union { u32 u; h2 h; } v; v.u = u; return v.h;
}
static __device__ __forceinline__ u32 pk2h(float a, float b) {
  union { _Float16 h[2]; u32 u; } v;
  v.h[0] = (_Float16)a; v.h[1] = (_Float16)b; return v.u;
}
#if __has_builtin(__builtin_amdgcn_fdot2)
#define FDOT2(a, b, c) __builtin_amdgcn_fdot2((a), (b), (c), false)
#else
#define FDOT2(a, b, c) \
  ((c) + (float)(a)[0] * (float)(b)[0] + (float)(a)[1] * (float)(b)[1])
#endif

// ---------------------------------------------------------------------------
// Heavy GEMM, BK=128 (proven R12/R13): 128x128 tile, 4 waves, single-buffered
// [128][128] LDS per operand (A and B both staged), XOR-slot swizzle
// (slot^(row&15)), XCD swizzle.  One barrier-pair + drain per 128 K.
// K%128==0.  NOTE (R14): B-direct-from-L2 was tried and regressed 51->87us
// (exposed per-kk global load latency); B must stay LDS-staged.
// ---------------------------------------------------------------------------
template <int EPI>
__global__ __launch_bounds__(256) void gemm_bt128(
    const u16* __restrict__ A, const u16* __restrict__ W,
    const float* __restrict__ bias, const float* __restrict__ scale,
    const float* __restrict__ shift, u16* __restrict__ Cp,
    int K, int ldc) {
  __shared__ u16 As[128 * 128];
  __shared__ u16 Bs[128 * 128];
  const u32 gx = gridDim.x;
  const u32 nwg = gx * gridDim.y;
  u32 lid = blockIdx.y * gx + blockIdx.x;
  if ((nwg & 7u) == 0u) {
    const u32 cpx = nwg >> 3;
    lid = (lid & 7u) * cpx + (lid >> 3);
  }
  const int bm = (int)(lid / gx) * 128;
  const int bn = (int)(lid % gx) * 128;
  const int tid = threadIdx.x;
  const int lane = tid & 63;
  const int wid = tid >> 6;
  const int wr = wid >> 1, wc = wid & 1;
  const int lg = lane >> 4, lr = lane & 15;

  f32x4 acc[4][4];
#pragma unroll
  for (int i = 0; i < 4; ++i)
#pragma unroll
    for (int j = 0; j < 4; ++j) acc[i][j] = (f32x4){0.f, 0.f, 0.f, 0.f};

  const int srow16 = tid >> 4;
  const int gslot = ((tid & 15) ^ srow16) * 8;
  const u16* Ag[8];
  const u16* Wg[8];
#pragma unroll
  for (int p = 0; p < 8; ++p) {
    Ag[p] = A + (size_t)(bm + p * 16 + srow16) * K + gslot;
    Wg[p] = W + (size_t)(bn + p * 16 + srow16) * K + gslot;
  }
  u16* dA = &As[tid * 8];
  u16* dB = &Bs[tid * 8];

  for (int k0 = 0; k0 < K; k0 += 128) {
#pragma unroll
    for (int p = 0; p < 8; ++p) {
      gl16(Ag[p] + k0, dA + p * 2048);
      gl16(Wg[p] + k0, dB + p * 2048);
    }
    __syncthreads();
#pragma unroll
    for (int kk = 0; kk < 4; ++kk) {
      const int slot = ((kk * 4 + lg) ^ lr) * 8;
      bf16x8 af[4], bfv[4];
#pragma unroll
      for (int i = 0; i < 4; ++i)
        af[i] = *(const bf16x8*)&As[(wr * 64 + i * 16 + lr) * 128 + slot];
#pragma unroll
      for (int j = 0; j < 4; ++j)
        bfv[j] = *(const bf16x8*)&Bs[(wc * 64 + j * 16 + lr) * 128 + slot];
#pragma unroll
      for (int i = 0; i < 4; ++i)
#pragma unroll
        for (int j = 0; j < 4; ++j)
          acc[i][j] = __builtin_amdgcn_mfma_f32_16x16x32_bf16(
              af[i], bfv[j], acc[i][j], 0, 0, 0);
    }
    __syncthreads();
  }

#pragma unroll
  for (int i = 0; i < 4; ++i) {
#pragma unroll
    for (int j = 0; j < 4; ++j) {
#pragma unroll
      for (int r = 0; r < 4; ++r) {
        const int grow = bm + wr * 64 + i * 16 + lg * 4 + r;
        const int gcol = bn + wc * 64 + j * 16 + lr;
        float v = acc[i][j][r] + bias[gcol];
        v = fmaxf(v, 0.f);
        if (EPI == 1) v = v * scale[gcol] + shift[gcol];
        Cp[(size_t)grow * ldc + gcol] = f2bf(v);
      }
    }
  }
}

// ---------------------------------------------------------------------------
// BK=32 GEMM (K=96 layer-1 GEMM1): round-4 proven version.
// ---------------------------------------------------------------------------
template <int EPI>
__global__ __launch_bounds__(256) void gemm_bt(
    const u16* __restrict__ A, const u16* __restrict__ W,
    const float* __restrict__ bias, const float* __restrict__ scale,
    const float* __restrict__ shift, u16* __restrict__ Cp,
    int K, int ldc, int coff) {
  __shared__ u16 As[128 * 32];
  __shared__ u16 Bs[128 * 32];
  const u32 gx = gridDim.x;
  const u32 nwg = gx * gridDim.y;
  u32 lid = blockIdx.y * gx + blockIdx.x;
  if ((nwg & 7u) == 0u) {
    const u32 cpx = nwg >> 3;
    lid = (lid & 7u) * cpx + (lid >> 3);
  }
  const int bm = (int)(lid / gx) * 128;
  const int bn = (int)(lid % gx) * 128;
  const int tid = threadIdx.x;
  const int lane = tid & 63;
  const int wid = tid >> 6;
  const int wr = wid >> 1, wc = wid & 1;
  const int lg = lane >> 4, lr = lane & 15;

  f32x4 acc[4][4];
#pragma unroll
  for (int i = 0; i < 4; ++i)
#pragma unroll
    for (int j = 0; j < 4; ++j) acc[i][j] = (f32x4){0.f, 0.f, 0.f, 0.f};

  const int srow = tid >> 2;
  const int c8 = (tid & 3) * 8;
  const u16* Ag0 = A + (size_t)(bm + srow) * K + c8;
  const u16* Ag1 = A + (size_t)(bm + 64 + srow) * K + c8;
  const u16* Wg0 = W + (size_t)(bn + srow) * K + c8;
  const u16* Wg1 = W + (size_t)(bn + 64 + srow) * K + c8;
  u16* lA0 = &As[tid * 8];
  u16* lA1 = &As[2048 + tid * 8];
  u16* lB0 = &Bs[tid * 8];
  u16* lB1 = &Bs[2048 + tid * 8];

  for (int k0 = 0; k0 < K; k0 += 32) {
    gl16(Ag0 + k0, lA0);
    gl16(Ag1 + k0, lA1);
    gl16(Wg0 + k0, lB0);
    gl16(Wg1 + k0, lB1);
    __syncthreads();
    bf16x8 af[4], bfv[4];
#pragma unroll
    for (int i = 0; i < 4; ++i)
      af[i] = *(const bf16x8*)&As[(wr * 64 + i * 16 + lr) * 32 + lg * 8];
#pragma unroll
    for (int j = 0; j < 4; ++j)
      bfv[j] = *(const bf16x8*)&Bs[(wc * 64 + j * 16 + lr) * 32 + lg * 8];
#pragma unroll
    for (int i = 0; i < 4; ++i)
#pragma unroll
      for (int j = 0; j < 4; ++j)
        acc[i][j] = __builtin_amdgcn_mfma_f32_16x16x32_bf16(af[i], bfv[j],
                                                            acc[i][j], 0, 0, 0);
    __syncthreads();
  }

#pragma unroll
  for (int i = 0; i < 4; ++i) {
#pragma unroll
    for (int j = 0; j < 4; ++j) {
#pragma unroll
      for (int r = 0; r < 4; ++r) {
        const int grow = bm + wr * 64 + i * 16 + lg * 4 + r;
        const int gcol = bn + wc * 64 + j * 16 + lr;
        float v = acc[i][j][r] + bias[gcol];
        v = fmaxf(v, 0.f);
        if (EPI == 1) v = v * scale[gcol] + shift[gcol];
        Cp[(size_t)grow * ldc + coff + gcol] = f2bf(v);
      }
    }
  }
}

// ---------------------------------------------------------------------------
// Fused head (proven R13): 16 graph rows per block, intermediates in LDS
// fragment-major; swapped-operand mfma(b,a) epilogue mapping.
// ---------------------------------------------------------------------------
static __device__ __forceinline__ void head_stage2(
    const u16* Sa, u16* So, int kofs, const u16* __restrict__ W, int ldw,
    const float* __restrict__ bias, int KT, int w, int l, int lr, int lg) {
  f32x4 acc[2];
  acc[0] = (f32x4){0.f, 0.f, 0.f, 0.f};
  acc[1] = (f32x4){0.f, 0.f, 0.f, 0.f};
  for (int t = 0; t < KT; ++t) {
    bf16x8 a = *(const bf16x8*)&Sa[t * 512 + l * 8];
#pragma unroll
    for (int j = 0; j < 2; ++j) {
      bf16x8 b = *(const bf16x8*)&W[(size_t)(w * 32 + j * 16 + lr) * ldw +
                                    t * 32 + lg * 8];
      acc[j] = __builtin_amdgcn_mfma_f32_16x16x32_bf16(b, a, acc[j], 0, 0, 0);
    }
  }
#pragma unroll
  for (int j = 0; j < 2; ++j) {
    const int c0 = w * 32 + j * 16 + lg * 4;
    const float4 bs = *(const float4*)&bias[c0];
    const float v0 = fmaxf(acc[j][0] + bs.x, 0.f);
    const float v1 = fmaxf(acc[j][1] + bs.y, 0.f);
    const float v2 = fmaxf(acc[j][2] + bs.z, 0.f);
    const float v3 = fmaxf(acc[j][3] + bs.w, 0.f);
    uint2 r;
    r.x = (u32)f2bf(v0) | ((u32)f2bf(v1) << 16);
    r.y = (u32)f2bf(v2) | ((u32)f2bf(v3) << 16);
    const int k0 = kofs + c0;
    *(uint2*)&So[(k0 >> 5) * 512 + ((k0 & 31) >> 3) * 128 + lr * 8 + (k0 & 7)] = r;
  }
}

static __device__ __forceinline__ void head_stage1(
    const u16* Sa, u16* So, int kofs, const u16* __restrict__ W, int ldw,
    const float* __restrict__ bias, int KT, int w, int l, int lr, int lg) {
  f32x4 acc = (f32x4){0.f, 0.f, 0.f, 0.f};
  for (int t = 0; t < KT; ++t) {
    bf16x8 a = *(const bf16x8*)&Sa[t * 512 + l * 8];
    bf16x8 b = *(const bf16x8*)&W[(size_t)(w * 16 + lr) * ldw + t * 32 + lg * 8];
    acc = __builtin_amdgcn_mfma_f32_16x16x32_bf16(b, a, acc, 0, 0, 0);
  }
  const int c0 = w * 16 + lg * 4;
  const float4 bs = *(const float4*)&bias[c0];
  const float v0 = fmaxf(acc[0] + bs.x, 0.f);
  const float v1 = fmaxf(acc[1] + bs.y, 0.f);
  const float v2 = fmaxf(acc[2] + bs.z, 0.f);
  const float v3 = fmaxf(acc[3] + bs.w, 0.f);
  uint2 r;
  r.x = (u32)f2bf(v0) | ((u32)f2bf(v1) << 16);
  r.y = (u32)f2bf(v2) | ((u32)f2bf(v3) << 16);
  const int k0 = kofs + c0;
  *(uint2*)&So[(k0 >> 5) * 512 + ((k0 & 31) >> 3) * 128 + lr * 8 + (k0 & 7)] = r;
}

__global__ __launch_bounds__(512) void head_fused(
    const u16* __restrict__ gbuf, const u16* __restrict__ fingb,
    const u16* __restrict__ wfcg, const float* __restrict__ fcg_b,
    const u16* __restrict__ wfp1, const float* __restrict__ fp1_b,
    const u16* __restrict__ wfp2, const float* __restrict__ fp2_b,
    const u16* __restrict__ wfb1, const float* __restrict__ fb1_b,
    const u16* __restrict__ wfb2, const float* __restrict__ fb2_b,
    const u16* __restrict__ wfb3, const float* __restrict__ fb3_b,
    const float* __restrict__ fb4_w, const float* __restrict__ fb4_b,
    float* __restrict__ out) {
  __shared__ u16 S[26624];
  const int g0 = blockIdx.x * 16;
  const int tid = threadIdx.x;
  const int w = tid >> 6, l = tid & 63;
  const int lr = l & 15, lg = l >> 4;

  for (int v = tid; v < 1024; v += 512) {
    const int r = v >> 6, c0 = (v & 63) * 8;
    uint4 d = *(const uint4*)&gbuf[(size_t)(g0 + r) * 512 + c0];
    *(uint4*)&S[(c0 >> 5) * 512 + ((c0 & 31) >> 3) * 128 + r * 8] = d;
  }
  __syncthreads();
  head_stage2(&S[0], &S[8192], 0, wfcg, 512, fcg_b, 16, w, l, lr, lg);
  {
    f32x4 acc = (f32x4){0.f, 0.f, 0.f, 0.f};
    for (int t = 0; t < 47; ++t) {
      bf16x8 a = *(const bf16x8*)&fingb[(size_t)(g0 + lr) * 1504 + t * 32 + lg * 8];
      bf16x8 b = *(const bf16x8*)&wfp1[(size_t)(w * 16 + lr) * 1504 + t * 32 + lg * 8];
      acc = __builtin_amdgcn_mfma_f32_16x16x32_bf16(b, a, acc, 0, 0, 0);
    }
    const int c0 = w * 16 + lg * 4;
    const float4 bs = *(const float4*)&fp1_b[c0];
    const float v0 = fmaxf(acc[0] + bs.x, 0.f);
    const float v1 = fmaxf(acc[1] + bs.y, 0.f);
    const float v2 = fmaxf(acc[2] + bs.z, 0.f);
    const float v3 = fmaxf(acc[3] + bs.w, 0.f);
    uint2 r;
    r.x = (u32)f2bf(v0) | ((u32)f2bf(v1) << 16);
    r.y = (u32)f2bf(v2) | ((u32)f2bf(v3) << 16);
    *(uint2*)&S[16384 + (c0 >> 5) * 512 + ((c0 & 31) >> 3) * 128 + lr * 8 +
                (c0 & 7)] = r;
  }
  __syncthreads();
  head_stage2(&S[16384], &S[8192], 256, wfp2, 128, fp2_b, 4, w, l, lr, lg);
  __syncthreads();
  head_stage2(&S[8192], &S[18432], 0, wfb1, 512, fb1_b, 16, w, l, lr, lg);
  __syncthreads();
  head_stage1(&S[18432], &S[22528], 0, wfb2, 256, fb2_b, 8, w, l, lr, lg);
  __syncthreads();
  if (w < 4) {
    f32x4 acc = (f32x4){0.f, 0.f, 0.f, 0.f};
    for (int t = 0; t < 4; ++t) {
      bf16x8 a = *(const bf16x8*)&S[22528 + t * 512 + l * 8];
      bf16x8 b = *(const bf16x8*)&wfb3[(size_t)(w * 16 + lr) * 128 + t * 32 + lg * 8];
      acc = __builtin_amdgcn_mfma_f32_16x16x32_bf16(b, a, acc, 0, 0, 0);
    }
    const int c0 = w * 16 + lg * 4;
    float* H3 = (float*)&S[24576];
#pragma unroll
    for (int r = 0; r < 4; ++r)
      H3[lr * 64 + c0 + r] = fmaxf(acc[r] + fb3_b[c0 + r], 0.f);
  }
  __syncthreads();
  if (tid < 32) {
    const int r = tid >> 1, o = tid & 1;
    const float* H3 = (const float*)&S[24576];
    float s = fb4_b[o];
#pragma unroll 8
    for (int k = 0; k < 64; ++k) s += H3[r * 64 + k] * fb4_w[o * 64 + k];
    out[(size_t)(g0 + r) * 2 + o] = 1.f / (1.f + expf(-s));
  }
}

// ---------------------------------------------------------------------------
// CSR build (edge list is static): deg histogram -> exclusive scan -> scatter.
// ---------------------------------------------------------------------------
__global__ void hist_deg(const int* __restrict__ dst, int* __restrict__ deg) {
  int e = blockIdx.x * blockDim.x + threadIdx.x;
  if (e < N_EDGES) atomicAdd(&deg[dst[e]], 1);
}

__global__ __launch_bounds__(1024) void scan_rowptr(const int* __restrict__ deg,
                                                    int* __restrict__ rowptr) {
  __shared__ int lds[1024];
  const int t = threadIdx.x;
  const int base = t * 64;
  int s = 0;
  for (int i = 0; i < 64; ++i) s += deg[base + i];
  lds[t] = s;
  __syncthreads();
  for (int ofs = 1; ofs < 1024; ofs <<= 1) {
    int v = (t >= ofs) ? lds[t - ofs] : 0;
    __syncthreads();
    lds[t] += v;
    __syncthreads();
  }
  int run = (t == 0) ? 0 : lds[t - 1];
  for (int i = 0; i < 64; ++i) {
    rowptr[base + i] = run;
    run += deg[base + i];
  }
  if (t == 1023) rowptr[65536] = run;
}

// consumes deg (countdown to zero); slot order within a node is arbitrary
__global__ void scatter_csr(const int* __restrict__ dst,
                            const int* __restrict__ rowptr,
                            int* __restrict__ deg, int* __restrict__ csr) {
  int e = blockIdx.x * blockDim.x + threadIdx.x;
  if (e >= N_EDGES) return;
  int d = dst[e];
  int pos = atomicSub(&deg[d], 1) - 1;
  csr[rowptr[d] + pos] = e;
}

// CSR-ordered edge data: src_s[i] = esrc[csr[i]]; ea16[i] = f16x2-packed ea row.
__global__ void prep_edges(const int* __restrict__ csr,
                           const int* __restrict__ esrc,
                           const float* __restrict__ ea,
                           int* __restrict__ src_s, u32* __restrict__ ea16) {
  int i = blockIdx.x * blockDim.x + threadIdx.x;
  if (i >= N_EDGES) return;
  const int eid = csr[i];
  src_s[i] = esrc[eid];
  const float* er = ea + (size_t)eid * 10;
  u32* o = ea16 + (size_t)i * 5;
  o[0] = pk2h(er[0], er[1]);
  o[1] = pk2h(er[2], er[3]);
  o[2] = pk2h(er[4], er[5]);
  o[3] = pk2h(er[6], er[7]);
  o[4] = pk2h(er[8], er[9]);
}

// Edge-lin weights -> packed f16 pairs, layers 1 (78 rows), 2 and 3 (512 each).
__global__ void ew_h16(const float* __restrict__ ew1, const float* __restrict__ ew2,
                       const float* __restrict__ ew3, u32* __restrict__ o1,
                       u32* __restrict__ o2, u32* __restrict__ o3) {
  int i = blockIdx.x * blockDim.x + threadIdx.x;  // 0..1101
  const float* src;
  u32* dst;
  if (i < 512) { src = ew2 + (size_t)i * 10; dst = o2 + i * 5; }
  else if (i < 1024) { src = ew3 + (size_t)(i - 512) * 10; dst = o3 + (i - 512) * 5; }
  else if (i < 1102) { src = ew1 + (size_t)(i - 1024) * 10; dst = o1 + (i - 1024) * 5; }
  else return;
#pragma unroll
  for (int k = 0; k < 5; ++k) dst[k] = pk2h(src[2 * k], src[2 * k + 1]);
}

// ---------------------------------------------------------------------------
// Node-centric fused aggregation, f16-dot2 variant (proven R11).
// ---------------------------------------------------------------------------
__global__ __launch_bounds__(128) void gather512d(
    const int* __restrict__ rowptr, const int* __restrict__ src_s,
    const u32* __restrict__ ea16, const u32* __restrict__ ew16,
    const float* __restrict__ eb, const u16* __restrict__ H,
    u16* __restrict__ T) {
  const int t = threadIdx.x;
  const int c4 = t * 4;
  h2 w[4][5];
#pragma unroll
  for (int j = 0; j < 4; ++j)
#pragma unroll
    for (int k = 0; k < 5; ++k) w[j][k] = b2h2(ew16[(c4 + j) * 5 + k]);
  float eb4[4];
#pragma unroll
  for (int j = 0; j < 4; ++j) eb4[j] = eb[c4 + j];

  const int dend = blockIdx.x * 8 + 8;
  for (int d = blockIdx.x * 8; d < dend; ++d) {
    uint2 hv = *(const uint2*)&H[(size_t)d * 512 + c4];
    float a0 = bf2f((u16)(hv.x & 0xffffu)), a1 = bf2f((u16)(hv.x >> 16));
    float a2 = bf2f((u16)(hv.y & 0xffffu)), a3 = bf2f((u16)(hv.y >> 16));
    const int i1 = rowptr[d + 1];
#pragma unroll 2
    for (int i = rowptr[d]; i < i1; ++i) {
      const int s = src_s[i];
      const u32* ep = ea16 + (size_t)i * 5;
      const h2 e0 = b2h2(ep[0]), e1 = b2h2(ep[1]), e2 = b2h2(ep[2]),
               e3 = b2h2(ep[3]), e4 = b2h2(ep[4]);
      uint2 hs = *(const uint2*)&H[(size_t)s * 512 + c4];
      float h0 = bf2f((u16)(hs.x & 0xffffu)), h1 = bf2f((u16)(hs.x >> 16));
      float h2v = bf2f((u16)(hs.y & 0xffffu)), h3 = bf2f((u16)(hs.y >> 16));
      float l0 = eb4[0], l1 = eb4[1], l2 = eb4[2], l3 = eb4[3];
      l0 = FDOT2(e0, w[0][0], l0); l0 = FDOT2(e1, w[0][1], l0);
      l0 = FDOT2(e2, w[0][2], l0); l0 = FDOT2(e3, w[0][3], l0);
      l0 = FDOT2(e4, w[0][4], l0);
      l1 = FDOT2(e0, w[1][0], l1); l1 = FDOT2(e1, w[1][1], l1);
      l1 = FDOT2(e2, w[1][2], l1); l1 = FDOT2(e3, w[1][3], l1);
      l1 = FDOT2(e4, w[1][4], l1);
      l2 = FDOT2(e0, w[2][0], l2); l2 = FDOT2(e1, w[2][1], l2);
      l2 = FDOT2(e2, w[2][2], l2); l2 = FDOT2(e3, w[2][3], l2);
      l2 = FDOT2(e4, w[2][4], l2);
      l3 = FDOT2(e0, w[3][0], l3); l3 = FDOT2(e1, w[3][1], l3);
      l3 = FDOT2(e2, w[3][2], l3); l3 = FDOT2(e3, w[3][3], l3);
      l3 = FDOT2(e4, w[3][4], l3);
      a0 += fmaxf(h0 + l0, 0.f);
      a1 += fmaxf(h1 + l1, 0.f);
      a2 += fmaxf(h2v + l2, 0.f);
      a3 += fmaxf(h3 + l3, 0.f);
    }
    uint2 r;
    r.x = (u32)f2bf(a0) | ((u32)f2bf(a1) << 16);
    r.y = (u32)f2bf(a2) | ((u32)f2bf(a3) << 16);
    *(uint2*)&T[(size_t)d * 512 + c4] = r;
  }
}

// Layer-1 variant, f16-dot2 (proven R12).
__global__ __launch_bounds__(128) void gather78d(
    const int* __restrict__ rowptr, const int* __restrict__ src_s,
    const u32* __restrict__ ea16, const u32* __restrict__ ew16,
    const float* __restrict__ eb, const float* __restrict__ X,
    u16* __restrict__ T) {
  const int t = threadIdx.x;
  const bool act = t < 78;
  h2 w[5];
  float ebv = 0.f;
  if (act) {
#pragma unroll
    for (int k = 0; k < 5; ++k) w[k] = b2h2(ew16[t * 5 + k]);
    ebv = eb[t];
  }
  const int dend = blockIdx.x * 8 + 8;
  for (int d = blockIdx.x * 8; d < dend; ++d) {
    float acc = act ? X[(size_t)d * 78 + t] : 0.f;
    const int i1 = rowptr[d + 1];
    for (int i = rowptr[d]; i < i1; ++i) {
      const int s = src_s[i];
      const u32* ep = ea16 + (size_t)i * 5;
      const h2 e0 = b2h2(ep[0]), e1 = b2h2(ep[1]), e2 = b2h2(ep[2]),
               e3 = b2h2(ep[3]), e4 = b2h2(ep[4]);
      if (act) {
        float el = ebv;
        el = FDOT2(e0, w[0], el); el = FDOT2(e1, w[1], el);
        el = FDOT2(e2, w[2], el); el = FDOT2(e3, w[3], el);
        el = FDOT2(e4, w[4], el);
        acc += fmaxf(X[(size_t)s * 78 + t] + el, 0.f);
      }
    }
    if (t < 96) T[(size_t)d * 96 + t] = act ? f2bf(acc) : (u16)0;
  }
}

// ---------------------------------------------------------------------------
// Consolidated prep: 12 f32->bf16 (pad) conversions in one launch.
// ---------------------------------------------------------------------------
struct CvtJob { const float* in; u16* out; int cin; int cout; };
struct CvtJobs { CvtJob j[12]; int blk_ofs[13]; };

__global__ __launch_bounds__(256) void cvt_multi(CvtJobs jb, int njobs) {
  int b = blockIdx.x;
  int ji = 0;
  while (ji + 1 < njobs && b >= jb.blk_ofs[ji + 1]) ++ji;
  const CvtJob J = jb.j[ji];
  int idx = (b - jb.blk_ofs[ji]) * 256 + threadIdx.x;
  int r = idx / J.cout, c = idx - r * J.cout;
  int tot_blocks = jb.blk_ofs[ji + 1] - jb.blk_ofs[ji];
  if (idx >= tot_blocks * 256) return;
  if (idx >= ((tot_blocks * 256) / J.cout) * J.cout && c >= J.cout) return;
  J.out[idx] = (c < J.cin) ? f2bf(J.in[(size_t)r * J.cin + c]) : (u16)0;
}

// BN folded to per-channel affine, all 3 layers in one launch
struct BnJobs { const float* g[3]; const float* b[3]; const float* m[3];
                const float* v[3]; };
__global__ void bn_affine3(BnJobs p, float* __restrict__ bnS) {
  int i = blockIdx.x * blockDim.x + threadIdx.x;  // 0..1535
  int l = i >> 9, c = i & 511;
  float s = p.g[l][c] * rsqrtf(p.v[l][c] + 1e-5f);
  bnS[l * 1024 + c] = s;
  bnS[l * 1024 + 512 + c] = p.b[l][c] - p.m[l][c] * s;
}

// segment starts from sorted batch: start[g] = first node with batch >= g
__global__ void seg_starts(const int* __restrict__ batch, int* __restrict__ start,
                           int n, int ngraphs) {
  int i = blockIdx.x * blockDim.x + threadIdx.x;
  if (i >= n) return;
  int b = batch[i];
  int prev = (i == 0) ? -1 : batch[i - 1];
  for (int g = prev + 1; g <= b; ++g) start[g] = i;
  if (i == n - 1)
    for (int g = b + 1; g <= ngraphs; ++g) start[g] = n;
}

// plain f32 -> bf16 with column padding (finger, runs after GNN layers)
__global__ void cvt_pad(const float* __restrict__ in, u16* __restrict__ out,
                        int rows, int cin, int cout) {
  int idx = blockIdx.x * blockDim.x + threadIdx.x;
  if (idx >= rows * cout) return;
  int rrow = idx / cout, j = idx - rrow * cout;
  out[idx] = (j < cin) ? f2bf(in[(size_t)rrow * cin + j]) : (u16)0;
}

// global_add_pool (block per graph, thread per channel), bf16 in/out
__global__ void pool_sum(const u16* __restrict__ H, const int* __restrict__ start,
                         u16* __restrict__ g) {
  int gi = blockIdx.x, c = threadIdx.x;
  int s = start[gi], e = start[gi + 1];
  float acc = 0.f;
  for (int i = s; i < e; ++i) acc += bf2f(H[(size_t)i * 512 + c]);
  g[gi * 512 + c] = f2bf(acc);
}

// ---------------------------------------------------------------------------
#define CDIV(a, b) (((a) + (b)-1) / (b))

extern "C" void kernel_launch(void* const* d_in, const int* in_sizes, int n_in,
                              void* d_out, int out_size, void* d_ws, size_t ws_size,
                              hipStream_t stream) {
  const float* x = (const float*)d_in[0];
  const float* finger = (const float*)d_in[1];
  const float* ea = (const float*)d_in[2];
  const int* eidx = (const int*)d_in[3];
  const int* batch = (const int*)d_in[4];
  const int* esrc = eidx;
  const int* edst = eidx + N_EDGES;

  const float* P[49];
  for (int i = 5; i < 49; ++i) P[i] = (const float*)d_in[i];
  const float* fcg_w = P[35]; const float* fcg_b = P[36];
  const float* fp1_w = P[37]; const float* fp1_b = P[38];
  const float* fp2_w = P[39]; const float* fp2_b = P[40];
  const float* fb1_w = P[41]; const float* fb1_b = P[42];
  const float* fb2_w = P[43]; const float* fb2_b = P[44];
  const float* fb3_w = P[45]; const float* fb3_b = P[46];
  const float* fb4_w = P[47]; const float* fb4_b = P[48];

  // ---- workspace layout (~142 MB total) ----
  size_t off = 0;
  char* base = (char*)d_ws;
  auto alloc = [&](size_t bytes) -> void* {
    void* p = base + off;
    off = (off + bytes + 255) & ~(size_t)255;
    return p;
  };
  char* BA = (char*)alloc((size_t)N_NODES * 512 * 2);  // ping buffer (67 MB)
  char* BB = (char*)alloc((size_t)N_NODES * 512 * 2);  // pong buffer (67 MB)
  u16* w11 = (u16*)alloc(256 * 96 * 2);
  u16* w12 = (u16*)alloc(512 * 256 * 2);
  u16* w21 = (u16*)alloc(512 * 512 * 2);
  u16* w22 = (u16*)alloc(512 * 512 * 2);
  u16* w31 = (u16*)alloc(512 * 512 * 2);
  u16* w32 = (u16*)alloc(512 * 512 * 2);
  u16* wfcg = (u16*)alloc(256 * 512 * 2);
  u16* wfp1 = (u16*)alloc(128 * 1504 * 2);
  u16* wfp2 = (u16*)alloc(256 * 128 * 2);
  u16* wfb1 = (u16*)alloc(256 * 512 * 2);
  u16* wfb2 = (u16*)alloc(128 * 256 * 2);
  u16* wfb3 = (u16*)alloc(64 * 128 * 2);
  float* bnS = (float*)alloc(6 * 512 * 4);
  int* start = (int*)alloc(2049 * 4);
  int* deg = (int*)alloc(65536 * 4);
  int* rowptr = (int*)alloc(65537 * 4);
  int* csr = (int*)alloc(131072 * 4);
  int* src_s = (int*)alloc(131072 * 4);
  u32* ea16 = (u32*)alloc((size_t)131072 * 5 * 4);
  u32* ew16a = (u32*)alloc(512 * 5 * 4);
  u32* ew16b = (u32*)alloc(512 * 5 * 4);
  u32* ew16c = (u32*)alloc(128 * 5 * 4);
  if (off > ws_size) return;  // workspace insufficient; bail

  // head buffers carved from BA (free after the GNN layers)
  u16* fingb = (u16*)BA;                  // 2048*1504*2 = 6,160,384 B
  u16* gbuf = (u16*)(BA + 6160384);       // 2048*512*2  = 2,097,152 B

  // ---- consolidated parameter prep (1 launch for 12 conversions) ----
  {
    CvtJobs jb;
    const float* ins[12] = {P[5 + 2], P[5 + 4], P[15 + 2], P[15 + 4], P[25 + 2],
                            P[25 + 4], fcg_w, fp1_w, fp2_w, fb1_w, fb2_w, fb3_w};
    u16* outs[12] = {w11, w12, w21, w22, w31, w32, wfcg, wfp1, wfp2, wfb1,
                     wfb2, wfb3};
    int rows[12] = {256, 512, 512, 512, 512, 512, 256, 128, 256, 256, 128, 64};
    int cins[12] = {78, 256, 512, 512, 512, 512, 512, 1489, 128, 512, 256, 128};
    int couts[12] = {96, 256, 512, 512, 512, 512, 512, 1504, 128, 512, 256, 128};
    int acc = 0;
    for (int i = 0; i < 12; ++i) {
      jb.j[i].in = ins[i]; jb.j[i].out = outs[i];
      jb.j[i].cin = cins[i]; jb.j[i].cout = couts[i];
      jb.blk_ofs[i] = acc;
      acc += CDIV(rows[i] * couts[i], 256);
    }
    jb.blk_ofs[12] = acc;
    cvt_multi<<<acc, 256, 0, stream>>>(jb, 12);
  }
  {
    BnJobs bj;
    for (int l = 0; l < 3; ++l) {
      int pb = 5 + 10 * l;
      bj.g[l] = P[pb + 6]; bj.b[l] = P[pb + 7];
      bj.m[l] = P[pb + 8]; bj.v[l] = P[pb + 9];
    }
    bn_affine3<<<6, 256, 0, stream>>>(bj, bnS);
  }
  seg_starts<<<CDIV(N_NODES, 256), 256, 0, stream>>>(batch, start, N_NODES, N_GRAPHS);
  ew_h16<<<5, 256, 0, stream>>>(P[5], P[15], P[25], ew16c, ew16a, ew16b);

  // ---- CSR build (once; edge list is static) ----
  hipMemsetAsync(deg, 0, 65536 * 4, stream);
  hist_deg<<<CDIV(N_EDGES, 256), 256, 0, stream>>>(edst, deg);
  scan_rowptr<<<1, 1024, 0, stream>>>(deg, rowptr);
  scatter_csr<<<CDIV(N_EDGES, 256), 256, 0, stream>>>(edst, rowptr, deg, csr);
  prep_edges<<<CDIV(N_EDGES, 256), 256, 0, stream>>>(csr, esrc, ea, src_s, ea16);

  // ---- layer 1 (Cin=78): T1->BB, U1->BA, H1->BB ----
  gather78d<<<N_NODES / 8, 128, 0, stream>>>(rowptr, src_s, ea16, ew16c, P[6], x,
                                             (u16*)BB);
  gemm_bt<0><<<dim3(2, 512), 256, 0, stream>>>((u16*)BB, w11, P[5 + 3], nullptr,
                                               nullptr, (u16*)BA, 96, 256, 0);
  gemm_bt128<1><<<dim3(4, 512), 256, 0, stream>>>((u16*)BA, w12, P[5 + 5], bnS,
                                                  bnS + 512, (u16*)BB, 256, 512);

  // ---- layer 2: H1 in BB -> T2 in BA -> U2 in BB -> H2 in BA ----
  gather512d<<<N_NODES / 8, 128, 0, stream>>>(rowptr, src_s, ea16, ew16a, P[16],
                                              (const u16*)BB, (u16*)BA);
  gemm_bt128<0><<<dim3(4, 512), 256, 0, stream>>>((u16*)BA, w21, P[15 + 3], nullptr,
                                                  nullptr, (u16*)BB, 512, 512);
  gemm_bt128<1><<<dim3(4, 512), 256, 0, stream>>>((u16*)BB, w22, P[15 + 5],
                                                  bnS + 1024, bnS + 1024 + 512,
                                                  (u16*)BA, 512, 512);

  // ---- layer 3: H2 in BA -> T3 in BB -> U3 in BA -> H3 in BB ----
  gather512d<<<N_NODES / 8, 128, 0, stream>>>(rowptr, src_s, ea16, ew16b, P[26],
                                              (const u16*)BA, (u16*)BB);
  gemm_bt128<0><<<dim3(4, 512), 256, 0, stream>>>((u16*)BB, w31, P[25 + 3], nullptr,
                                                  nullptr, (u16*)BA, 512, 512);
  gemm_bt128<1><<<dim3(4, 512), 256, 0, stream>>>((u16*)BA, w32, P[25 + 5],
                                                  bnS + 2048, bnS + 2048 + 512,
                                                  (u16*)BB, 512, 512);

  // ---- pool + fused head (H3 in BB; fingb/gbuf live in BA, now free) ----
  pool_sum<<<N_GRAPHS, 512, 0, stream>>>((const u16*)BB, start, gbuf);
  cvt_pad<<<CDIV(N_GRAPHS * 1504, 256), 256, 0, stream>>>(finger, fingb, N_GRAPHS,
                                                          1489, 1504);
  head_fused<<<N_GRAPHS / 16, 512, 0, stream>>>(
      gbuf, fingb, wfcg, fcg_b, wfp1, fp1_b, wfp2, fp2_b, wfb1, fb1_b, wfb2,
      fb2_b, wfb3, fb3_b, fb4_w, fb4_b, (float*)d_out);
}